// Round 6
// baseline (169.853 us; speedup 1.0000x reference)
//
#include <hip/hip_runtime.h>
#include <hip/hip_bf16.h>
#include <hip/hip_fp16.h>
#include <math.h>

// Decoder: out[e] = sigmoid(relu( W2 . relu( W1 * [x[src]; x[dst]] + b1 ) + b2 ))
// Factorized: Y[n][0:128] = W1_left*x[n] + b1 ; Y[n][128:256] = W1_right*x[n]
//             out[e] = sigmoid(relu( W2 . relu(Yl[src]+Yr[dst]) + b2 ))
// R6: Phase A rebuilt per-wave/barrier-free. R5 counters showed concurrency
//     starvation (occ 16%, ~5 waves/CU, 22k-cycle wave lifetimes): 33KB LDS
//     capped 4 blocks/CU and 3 barriers ganged waves through lockstep phases.
//     Now: 64-thread blocks, 32x64 tile/wave, A-frags direct from global
//     (16 fully-used 128B lines/instr), B from packed W1F, zero barriers,
//     5KB wave-private LDS only for the C-transpose (coalesced Y stores).

typedef short    s16x4 __attribute__((ext_vector_type(4)));
typedef short    s16x8 __attribute__((ext_vector_type(8)));
typedef float    f32x4 __attribute__((ext_vector_type(4)));
typedef _Float16 h16x8 __attribute__((ext_vector_type(8)));

#define D    128
#define CWLD 80        // LDS transpose row stride (shorts): 160B -> 16B-aligned, quads on disjoint banks

static __device__ inline short f2bf(float f) {
    unsigned u = __builtin_bit_cast(unsigned, f);
    unsigned r = (u + 0x7FFFu + ((u >> 16) & 1u)) >> 16;
    return (short)r;
}

// ---------------- pack W1 -> bf16 fragment order ----------------
// W1F[g*8 .. g*8+8) , g = cs*1024 + j*256 + c*64 + lane
//   o  = cs*64 + j*16 + (lane&15)           (Y output col)
//   kb = c*32 + (lane>>4)*8                 (k offset)
//   B[o][k] = W1[o&127][(o>>7)*128 + k]
__global__ __launch_bounds__(256) void pack_w1_kernel(
    const float* __restrict__ W1, short* __restrict__ W1F)
{
    int g    = blockIdx.x * 256 + threadIdx.x;   // 0..4095
    int lane = g & 63;
    int c    = (g >> 6) & 3;
    int j    = (g >> 8) & 3;
    int cs   = g >> 10;
    int o    = cs * 64 + j * 16 + (lane & 15);
    int kb   = c * 32 + (lane >> 4) * 8;
    const float* wp = W1 + (size_t)(o & 127) * 256 + (o >> 7) * 128 + kb;
    float4 u0 = *(const float4*)wp;
    float4 u1 = *(const float4*)(wp + 4);
    s16x8 v = { f2bf(u0.x), f2bf(u0.y), f2bf(u0.z), f2bf(u0.w),
                f2bf(u1.x), f2bf(u1.y), f2bf(u1.z), f2bf(u1.w) };
    *(s16x8*)&W1F[(size_t)g * 8] = v;
}

// ---------------- Phase A: per-wave 32 rows x 64 cols, no barriers ----------------
__global__ __launch_bounds__(64) void precompute_kernel(
    const float* __restrict__ x,    // [N,128]
    const short* __restrict__ W1F,  // packed bf16 fragments
    const float* __restrict__ b1,   // [128]
    _Float16*    __restrict__ Y,    // [N,256]
    int N)
{
    __shared__ _Float16 Cw[32 * CWLD];   // 5120 B, wave-private

    const int lane = threadIdx.x;        // single wave
    const int quad = lane >> 4, l15 = lane & 15;
    const int m0   = blockIdx.x * 32;
    const int cs   = blockIdx.y;         // col slice: cols cs*64 .. +63

    // ---- A raw loads first (HBM): 2 row-tiles x 4 k-chunks x 32B/lane
    float4 ar[2][4][2];
    #pragma unroll
    for (int i = 0; i < 2; ++i) {
        int m = m0 + i * 16 + l15; if (m >= N) m = N - 1;
        const float* xp = &x[(size_t)m * D + quad * 8];
        #pragma unroll
        for (int c = 0; c < 4; ++c) {
            ar[i][c][0] = *(const float4*)(xp + c * 32);
            ar[i][c][1] = *(const float4*)(xp + c * 32 + 4);
        }
    }

    // ---- B frags: coalesced 16B/lane from W1F (L2-hot)
    s16x8 bf[4][4];   // [k-chunk][col-tile]
    #pragma unroll
    for (int j = 0; j < 4; ++j)
        #pragma unroll
        for (int c = 0; c < 4; ++c)
            bf[c][j] = *(const s16x8*)&W1F[(size_t)(((cs * 4 + j) * 4 + c) * 64 + lane) * 8];

    // ---- MFMA
    f32x4 acc[2][4] = {};   // [row-tile][col-tile]
    #pragma unroll
    for (int c = 0; c < 4; ++c) {
        s16x8 af[2];
        #pragma unroll
        for (int i = 0; i < 2; ++i)
            af[i] = (s16x8){ f2bf(ar[i][c][0].x), f2bf(ar[i][c][0].y),
                             f2bf(ar[i][c][0].z), f2bf(ar[i][c][0].w),
                             f2bf(ar[i][c][1].x), f2bf(ar[i][c][1].y),
                             f2bf(ar[i][c][1].z), f2bf(ar[i][c][1].w) };
        #pragma unroll
        for (int i = 0; i < 2; ++i)
            #pragma unroll
            for (int j = 0; j < 4; ++j)
                acc[i][j] = __builtin_amdgcn_mfma_f32_16x16x32_bf16(
                    af[i], bf[c][j], acc[i][j], 0, 0, 0);
    }

    // ---- bias (uniform per block: cs<2 -> left half)
    float b1v[4];
    #pragma unroll
    for (int j = 0; j < 4; ++j)
        b1v[j] = (cs < 2) ? b1[cs * 64 + j * 16 + l15] : 0.f;

    // ---- transpose through wave-private LDS (no barrier needed: same wave)
    // C/D layout: col = lane&15, row = quad*4 + reg
    #pragma unroll
    for (int i = 0; i < 2; ++i)
        #pragma unroll
        for (int j = 0; j < 4; ++j)
            #pragma unroll
            for (int r = 0; r < 4; ++r)
                Cw[(i * 16 + quad * 4 + r) * CWLD + j * 16 + l15] =
                    (_Float16)(acc[i][j][r] + b1v[j]);

    __syncthreads();   // single-wave: compiles to lgkmcnt drain (+cheap barrier)

    // ---- coalesced store: per pass, 8 rows x 128B (one full line per row)
    #pragma unroll
    for (int p = 0; p < 4; ++p) {
        int row = p * 8 + (lane >> 3);
        int m   = m0 + row;
        if (m < N) {
            h16x8 v = *(const h16x8*)&Cw[row * CWLD + (lane & 7) * 8];
            *(h16x8*)&Y[(size_t)m * 256 + cs * 64 + (lane & 7) * 8] = v;
        }
    }
}

// ---------------- Phase B: per-edge streaming gather + dot(128) + sigmoid
__global__ __launch_bounds__(256) void edge_kernel(
    const _Float16* __restrict__ Y,   // [N,256]
    const int*      __restrict__ ei,  // [2,E]
    const float*    __restrict__ W2,  // [128]
    const float*    __restrict__ b2,  // [1]
    float*          __restrict__ out, // [E]
    int E)
{
    const int tid = threadIdx.x;
    const int sub = tid & 7;                    // 8 lanes per edge
    const int e   = blockIdx.x * 32 + (tid >> 3);

    float w2v[16];
    *(float4*)&w2v[0]  = *(const float4*)&W2[sub*16 + 0];
    *(float4*)&w2v[4]  = *(const float4*)&W2[sub*16 + 4];
    *(float4*)&w2v[8]  = *(const float4*)&W2[sub*16 + 8];
    *(float4*)&w2v[12] = *(const float4*)&W2[sub*16 + 12];

    if (e < E) {
        int src = ei[e];
        int dst = ei[E + e];
        const _Float16* pl = Y + (size_t)src * 256 + sub * 16;
        const _Float16* pr = Y + (size_t)dst * 256 + 128 + sub * 16;
        h16x8 a0 = *(const h16x8*)pl;
        h16x8 a1 = *(const h16x8*)(pl + 8);
        h16x8 c0 = *(const h16x8*)pr;
        h16x8 c1 = *(const h16x8*)(pr + 8);

        float s = 0.f;
        #pragma unroll
        for (int j = 0; j < 8; ++j) {
            float v = (float)a0[j] + (float)c0[j];
            v = fmaxf(v, 0.f);
            s = fmaf(v, w2v[j], s);
        }
        #pragma unroll
        for (int j = 0; j < 8; ++j) {
            float v = (float)a1[j] + (float)c1[j];
            v = fmaxf(v, 0.f);
            s = fmaf(v, w2v[8 + j], s);
        }
        s += __shfl_xor(s, 1);
        s += __shfl_xor(s, 2);
        s += __shfl_xor(s, 4);

        if (sub == 0) {
            s += b2[0];
            s = fmaxf(s, 0.f);
            out[e] = 1.0f / (1.0f + expf(-s));
        }
    }
}

// ---------------- fallback (fused edge-wise GEMM, fp32 inputs) ----------------
#define BM   128
#define BK   64
#define LDT  72

__global__ __launch_bounds__(256) void decoder_fallback_kernel(
    const float* __restrict__ x, const int* __restrict__ ei,
    const float* __restrict__ W1, const float* __restrict__ b1,
    const float* __restrict__ W2, const float* __restrict__ b2,
    float* __restrict__ out, int E)
{
    __shared__ int   nid[2][BM];
    __shared__ short At[BM * LDT];
    __shared__ short Bt[D * LDT];
    __shared__ float rowsum[BM][2];

    const int tid = threadIdx.x;
    const int e0  = blockIdx.x * BM;
    if (tid < BM) { int e = e0 + tid; nid[0][tid] = (e < E) ? ei[e] : 0; }
    else { int e = e0 + (tid - BM); nid[1][tid - BM] = (e < E) ? ei[E + e] : 0; }

    const int wid = tid >> 6, lane = tid & 63;
    const int wm = wid >> 1, wn = wid & 1;
    const int quad = lane >> 4, l15 = lane & 15;
    const int srow = tid >> 4, scol = (tid & 15) * 4;
    f32x4 acc[4][4] = {};
    __syncthreads();

    for (int t = 0; t < 4; ++t) {
        const int* ids = nid[t >> 1];
        const int kx = (t & 1) * BK, kw = t * BK;
        #pragma unroll
        for (int p = 0; p < 8; ++p) {
            int row = srow + p * 16;
            float4 v = *(const float4*)&x[(size_t)ids[row] * D + kx + scol];
            s16x4 bv = { f2bf(v.x), f2bf(v.y), f2bf(v.z), f2bf(v.w) };
            *(s16x4*)&At[row * LDT + scol] = bv;
        }
        #pragma unroll
        for (int p = 0; p < 8; ++p) {
            int n = srow + p * 16;
            float4 v = *(const float4*)&W1[n * 256 + kw + scol];
            s16x4 bv = { f2bf(v.x), f2bf(v.y), f2bf(v.z), f2bf(v.w) };
            *(s16x4*)&Bt[n * LDT + scol] = bv;
        }
        __syncthreads();
        #pragma unroll
        for (int c = 0; c < 2; ++c) {
            const int kc = c * 32;
            s16x8 af[4], bfr[4];
            #pragma unroll
            for (int i = 0; i < 4; ++i)
                af[i] = *(const s16x8*)&At[(wm*64 + i*16 + l15) * LDT + kc + quad*8];
            #pragma unroll
            for (int j = 0; j < 4; ++j)
                bfr[j] = *(const s16x8*)&Bt[(wn*64 + j*16 + l15) * LDT + kc + quad*8];
            #pragma unroll
            for (int i = 0; i < 4; ++i)
                #pragma unroll
                for (int j = 0; j < 4; ++j)
                    acc[i][j] = __builtin_amdgcn_mfma_f32_16x16x32_bf16(
                        af[i], bfr[j], acc[i][j], 0, 0, 0);
        }
        __syncthreads();
    }
    float b1v[4], w2v[4];
    #pragma unroll
    for (int j = 0; j < 4; ++j) {
        int col = wn*64 + j*16 + l15;
        b1v[j] = b1[col]; w2v[j] = W2[col];
    }
    float psum[16];
    #pragma unroll
    for (int t = 0; t < 16; ++t) psum[t] = 0.f;
    #pragma unroll
    for (int i = 0; i < 4; ++i)
        #pragma unroll
        for (int j = 0; j < 4; ++j)
            #pragma unroll
            for (int r = 0; r < 4; ++r) {
                float c = fmaxf(acc[i][j][r] + b1v[j], 0.f);
                psum[i*4 + r] += c * w2v[j];
            }
    #pragma unroll
    for (int off = 1; off < 16; off <<= 1)
        #pragma unroll
        for (int t = 0; t < 16; ++t)
            psum[t] += __shfl_xor(psum[t], off);
    if (l15 == 0) {
        #pragma unroll
        for (int i = 0; i < 4; ++i)
            #pragma unroll
            for (int r = 0; r < 4; ++r)
                rowsum[wm*64 + i*16 + quad*4 + r][wn] = psum[i*4 + r];
    }
    __syncthreads();
    if (tid < BM) {
        int e = e0 + tid;
        if (e < E) {
            float s = rowsum[tid][0] + rowsum[tid][1] + b2[0];
            s = fmaxf(s, 0.f);
            out[e] = 1.0f / (1.0f + expf(-s));
        }
    }
}

extern "C" void kernel_launch(void* const* d_in, const int* in_sizes, int n_in,
                              void* d_out, int out_size, void* d_ws, size_t ws_size,
                              hipStream_t stream) {
    const float* x  = (const float*)d_in[0];
    const int*   ei = (const int*)d_in[1];
    const float* W1 = (const float*)d_in[2];
    const float* b1 = (const float*)d_in[3];
    const float* W2 = (const float*)d_in[4];
    const float* b2 = (const float*)d_in[5];
    float* out = (float*)d_out;

    int E = in_sizes[1] / 2;
    int N = in_sizes[0] / D;

    size_t y_bytes = (size_t)N * 256 * sizeof(_Float16);       // 51.2 MB
    size_t need    = y_bytes + 32768 * sizeof(short);          // + 64 KB W1F
    if (ws_size >= need) {
        _Float16* Y   = (_Float16*)d_ws;
        short*    W1F = (short*)((char*)d_ws + y_bytes);
        pack_w1_kernel<<<16, 256, 0, stream>>>(W1, W1F);
        dim3 gridA((N + 31) / 32, 4);
        precompute_kernel<<<gridA, 64, 0, stream>>>(x, W1F, b1, Y, N);
        int gridB = (E + 31) / 32;
        edge_kernel<<<gridB, 256, 0, stream>>>(Y, ei, W2, b2, out, E);
    } else {
        int nblocks = (E + BM - 1) / BM;
        decoder_fallback_kernel<<<nblocks, 256, 0, stream>>>(
            x, ei, W1, b1, W2, b2, out, E);
    }
}